// Round 1
// 93.157 us; speedup vs baseline: 1.0559x; 1.0559x over previous
//
#include <hip/hip_runtime.h>

// Batched scalar neural-ODE, RK4, 99 steps, tiny 2->4->1 LeakyReLU MLP.
// One thread per batch element; 2048 waves total -> 2 waves/SIMD, VALU-issue-bound.
//
// dyn(s) is piecewise-linear in s with 4 knots. Factored form:
//   dyn(s) = M*s + K + sum_i g_i * |s - r_i|
//     M   = 0.505 * sum_i w_i*A_i            (uniform -> SGPR)
//     g_i = 0.495 * w_i*|A_i|                (uniform -> SGPR)
//     K   = b2 + 0.505 * sum_i w_i*C_i       (per-thread, C_i = u*U_i + b1_i)
//     r_i = -C_i / A_i                       (per-thread)
// Per dyn: 4 t-ops + 1 linear fma + 4-fma |t| chain = 9 VALU (was 13).
// Linear terms of stages 2-4 fold off base=fma(M,s,K):
//   M*(s+c*k)+K = fma(c*M, k, base); t_i = fma(c, k, d_i).
// -> 40 VALU/step (was 59).

#define NSTEP 100

__global__ __launch_bounds__(256, 2) void rk4_net_kernel(
    const float* __restrict__ x, const float* __restrict__ u,
    const float* __restrict__ W1, const float* __restrict__ b1,
    const float* __restrict__ W2, const float* __restrict__ b2,
    float* __restrict__ out, int B)
{
    const int b = blockIdx.x * blockDim.x + threadIdx.x;
    if (b >= B) return;

    // Uniform weights (W1 row-major (2,4): row 0 multiplies s, row 1 multiplies u)
    const float A0 = W1[0], A1 = W1[1], A2 = W1[2], A3 = W1[3];
    const float U0 = W1[4], U1 = W1[5], U2 = W1[6], U3 = W1[7];
    const float w0 = W2[0], w1 = W2[1], w2 = W2[2], w3 = W2[3];
    const float bias2 = b2[0];

    const float uu = u[b];
    float s = x[b];

    // Per-thread hidden-layer constants: C_i = u*W1[1][i] + b1[i]
    const float C0 = fmaf(uu, U0, b1[0]);
    const float C1 = fmaf(uu, U1, b1[1]);
    const float C2 = fmaf(uu, U2, b1[2]);
    const float C3 = fmaf(uu, U3, b1[3]);

    // Uniform slope / gains
    const float M  = 0.505f * (w0*A0 + w1*A1 + w2*A2 + w3*A3);
    const float hM = 0.5f * M;

    // Guard |A_i| ~ 0: knot goes away; 0.495*w_i*|C_i| folds into K.
    const bool t0g = __builtin_fabsf(A0) < 1e-20f;
    const bool t1g = __builtin_fabsf(A1) < 1e-20f;
    const bool t2g = __builtin_fabsf(A2) < 1e-20f;
    const bool t3g = __builtin_fabsf(A3) < 1e-20f;

    const float g0 = t0g ? 0.f : 0.495f * w0 * __builtin_fabsf(A0);
    const float g1 = t1g ? 0.f : 0.495f * w1 * __builtin_fabsf(A1);
    const float g2 = t2g ? 0.f : 0.495f * w2 * __builtin_fabsf(A2);
    const float g3 = t3g ? 0.f : 0.495f * w3 * __builtin_fabsf(A3);

    const float nI0 = t0g ? 0.f : (-1.0f / A0);
    const float nI1 = t1g ? 0.f : (-1.0f / A1);
    const float nI2 = t2g ? 0.f : (-1.0f / A2);
    const float nI3 = t3g ? 0.f : (-1.0f / A3);

    const float r0 = C0 * nI0, r1 = C1 * nI1, r2 = C2 * nI2, r3 = C3 * nI3;

    float K = fmaf(0.505f * w0, C0, bias2);
    K = fmaf(0.505f * w1, C1, K);
    K = fmaf(0.505f * w2, C2, K);
    K = fmaf(0.505f * w3, C3, K);
    if (t0g) K = fmaf(0.495f * w0, __builtin_fabsf(C0), K);
    if (t1g) K = fmaf(0.495f * w1, __builtin_fabsf(C1), K);
    if (t2g) K = fmaf(0.495f * w2, __builtin_fabsf(C2), K);
    if (t3g) K = fmaf(0.495f * w3, __builtin_fabsf(C3), K);

    auto step = [&](float sv) -> float {
        // stage 1
        const float d0 = sv - r0, d1 = sv - r1, d2 = sv - r2, d3 = sv - r3;
        const float base = fmaf(M, sv, K);
        float a = fmaf(g0, __builtin_fabsf(d0), base);
        a = fmaf(g1, __builtin_fabsf(d1), a);
        a = fmaf(g2, __builtin_fabsf(d2), a);
        const float k1 = fmaf(g3, __builtin_fabsf(d3), a);
        // stage 2: s + 0.5*k1
        float t0 = fmaf(0.5f, k1, d0), t1 = fmaf(0.5f, k1, d1);
        float t2 = fmaf(0.5f, k1, d2), t3 = fmaf(0.5f, k1, d3);
        float bb = fmaf(hM, k1, base);
        a = fmaf(g0, __builtin_fabsf(t0), bb);
        a = fmaf(g1, __builtin_fabsf(t1), a);
        a = fmaf(g2, __builtin_fabsf(t2), a);
        const float k2 = fmaf(g3, __builtin_fabsf(t3), a);
        // stage 3: s + 0.5*k2
        t0 = fmaf(0.5f, k2, d0); t1 = fmaf(0.5f, k2, d1);
        t2 = fmaf(0.5f, k2, d2); t3 = fmaf(0.5f, k2, d3);
        bb = fmaf(hM, k2, base);
        a = fmaf(g0, __builtin_fabsf(t0), bb);
        a = fmaf(g1, __builtin_fabsf(t1), a);
        a = fmaf(g2, __builtin_fabsf(t2), a);
        const float k3 = fmaf(g3, __builtin_fabsf(t3), a);
        // stage 4: s + k3
        t0 = d0 + k3; t1 = d1 + k3; t2 = d2 + k3; t3 = d3 + k3;
        bb = fmaf(M, k3, base);
        a = fmaf(g0, __builtin_fabsf(t0), bb);
        a = fmaf(g1, __builtin_fabsf(t1), a);
        a = fmaf(g2, __builtin_fabsf(t2), a);
        const float k4 = fmaf(g3, __builtin_fabsf(t3), a);
        // combine
        float sum = fmaf(2.0f, k2, k1);
        sum = fmaf(2.0f, k3, sum);
        sum += k4;
        return fmaf(0.16666667f, sum, sv);  // DT/6
    };

    // Output: out[b*100 + t]; buffer 4 steps, store float4 (base is 16B aligned).
    float4* o4 = (float4*)(out + (size_t)b * NSTEP);

    float4 v;
    v.x = s;                 // t = 0 is the initial state
    s = step(s); v.y = s;
    s = step(s); v.z = s;
    s = step(s); v.w = s;
    o4[0] = v;

#pragma unroll 1
    for (int c = 1; c < 25; ++c) {
        s = step(s); v.x = s;
        s = step(s); v.y = s;
        s = step(s); v.z = s;
        s = step(s); v.w = s;
        o4[c] = v;
    }
}

extern "C" void kernel_launch(void* const* d_in, const int* in_sizes, int n_in,
                              void* d_out, int out_size, void* d_ws, size_t ws_size,
                              hipStream_t stream) {
    const float* x  = (const float*)d_in[0];
    const float* u  = (const float*)d_in[1];
    const float* W1 = (const float*)d_in[2];
    const float* b1 = (const float*)d_in[3];
    const float* W2 = (const float*)d_in[4];
    const float* b2 = (const float*)d_in[5];
    float* out = (float*)d_out;

    const int B = in_sizes[0];
    const int block = 256;
    const int grid = (B + block - 1) / block;
    hipLaunchKernelGGL(rk4_net_kernel, dim3(grid), dim3(block), 0, stream,
                       x, u, W1, b1, W2, b2, out, B);
}